// Round 1
// baseline (357.552 us; speedup 1.0000x reference)
//
#include <hip/hip_runtime.h>

typedef __attribute__((ext_vector_type(8))) __bf16 bf16x8;
typedef __attribute__((ext_vector_type(4))) float f32x4;
typedef unsigned short u16;

#define BB 4
#define SS 2048
#define EE 1024
#define HH 4
#define DD 256
// BS = BB*SS = 8192 rows

__device__ __forceinline__ u16 f2bf(float f) {
  unsigned int u = __float_as_uint(f);
  u = (u + 0x7FFFu + ((u >> 16) & 1u)) >> 16;   // RNE
  return (u16)u;
}

// ---------------- cast f32 -> bf16 (vectorized) ----------------
__global__ __launch_bounds__(256) void cast_bf16_k(const float* __restrict__ in,
                                                   u16* __restrict__ out, int n4) {
  int i = blockIdx.x * 256 + threadIdx.x;
  if (i >= n4) return;
  float4 v = ((const float4*)in)[i];
  union { u16 s[4]; uint2 u; } o;
  o.s[0] = f2bf(v.x); o.s[1] = f2bf(v.y); o.s[2] = f2bf(v.z); o.s[3] = f2bf(v.w);
  ((uint2*)out)[i] = o.u;
}

// ---------------- transpose + cast: in[R][C] f32 -> out[C][R] bf16 ----------------
__global__ __launch_bounds__(256) void transpose_cast_k(const float* __restrict__ in,
                                                        u16* __restrict__ out, int R, int C) {
  __shared__ float tile[32][33];
  size_t moff = (size_t)blockIdx.z * R * C;
  in += moff; out += moff;
  int c0 = blockIdx.x * 32, r0 = blockIdx.y * 32;
  int tx = threadIdx.x, ty = threadIdx.y;   // 32 x 8
  #pragma unroll
  for (int i = 0; i < 4; ++i)
    tile[ty + 8*i][tx] = in[(size_t)(r0 + ty + 8*i) * C + c0 + tx];
  __syncthreads();
  #pragma unroll
  for (int i = 0; i < 4; ++i)
    out[(size_t)(c0 + ty + 8*i) * R + r0 + tx] = f2bf(tile[tx][ty + 8*i]);
}

// ---------------- 128x128 bf16 GEMM core: C = A[M][K] * Bt[N][K]^T ----------------
// 4 waves in 2x2, each wave 64x64 (4x4 16x16 frags). BK=64. XOR-swizzled LDS.
__device__ __forceinline__ void gemm128(const u16* __restrict__ A, int lda,
                                        const u16* __restrict__ Bt, int ldb,
                                        int row0, int col0, int K,
                                        u16* As, u16* Bs, f32x4 acc[4][4]) {
  int t = threadIdx.x;
  int lane = t & 63, w = t >> 6;
  int wr = w >> 1, wc = w & 1;
  int lr = lane & 15, kg = lane >> 4;
  f32x4 z = {0.f, 0.f, 0.f, 0.f};
  #pragma unroll
  for (int m = 0; m < 4; ++m)
    #pragma unroll
    for (int n = 0; n < 4; ++n) acc[m][n] = z;
  for (int kt = 0; kt < K; kt += 64) {
    __syncthreads();
    #pragma unroll
    for (int it = 0; it < 4; ++it) {
      int idx = (it*256 + t) * 8;          // 128x64 tile, 8 bf16 per thread-iter
      int row = idx >> 6, col = idx & 63;
      uint4 da = *(const uint4*)(A  + (size_t)(row0 + row) * lda + kt + col);
      uint4 db = *(const uint4*)(Bt + (size_t)(col0 + row) * ldb + kt + col);
      int bo = (row << 7) + (((col << 1)) ^ ((row & 7) << 4));
      *(uint4*)((char*)As + bo) = da;
      *(uint4*)((char*)Bs + bo) = db;
    }
    __syncthreads();
    #pragma unroll
    for (int kk = 0; kk < 2; ++kk) {
      bf16x8 af[4], bfr[4];
      #pragma unroll
      for (int m = 0; m < 4; ++m) {
        int row = wr*64 + m*16 + lr;
        int bo = (row << 7) + ((((kk << 6) + (kg << 4))) ^ ((row & 7) << 4));
        af[m] = *(const bf16x8*)((const char*)As + bo);
      }
      #pragma unroll
      for (int n = 0; n < 4; ++n) {
        int row = wc*64 + n*16 + lr;
        int bo = (row << 7) + ((((kk << 6) + (kg << 4))) ^ ((row & 7) << 4));
        bfr[n] = *(const bf16x8*)((const char*)Bs + bo);
      }
      #pragma unroll
      for (int m = 0; m < 4; ++m)
        #pragma unroll
        for (int n = 0; n < 4; ++n)
          acc[m][n] = __builtin_amdgcn_mfma_f32_16x16x32_bf16(af[m], bfr[n], acc[m][n], 0, 0, 0);
    }
  }
}

// ---------------- QKV projection ----------------
// xb [8192][1024] bf16 ; wt [12][256][1024] bf16 (transposed W) -> qkv [3][B][H][S][D] bf16
__global__ __launch_bounds__(256) void qkv_gemm_k(const u16* __restrict__ xb,
                                                  const u16* __restrict__ wt,
                                                  u16* __restrict__ qkv) {
  __shared__ u16 As[128*64], Bs[128*64];
  int bid = blockIdx.x;
  int mh = bid >> 7;               // 0..11  (qkvi*4 + h)
  int tt = bid & 127;
  int mt = tt & 63, nt = tt >> 6;  // 64 M-tiles, 2 N-tiles
  f32x4 acc[4][4];
  gemm128(xb, EE, wt + (size_t)mh * DD * EE, EE, mt*128, nt*128, EE, As, Bs, acc);
  int t = threadIdx.x, lane = t & 63, w = t >> 6;
  int wr = w >> 1, wc = w & 1, lr = lane & 15, kg = lane >> 4;
  int qi = mh >> 2, h = mh & 3;
  u16* outp = qkv + (size_t)qi * (BB*HH*SS*DD);
  #pragma unroll
  for (int m = 0; m < 4; ++m)
    #pragma unroll
    for (int n = 0; n < 4; ++n)
      #pragma unroll
      for (int j = 0; j < 4; ++j) {
        int r = mt*128 + wr*64 + m*16 + kg*4 + j;   // global row = b*2048+s
        int c = nt*128 + wc*64 + n*16 + lr;         // d
        int b = r >> 11, s = r & 2047;
        outp[(size_t)((b*HH + h) * SS + s) * DD + c] = f2bf(acc[m][n][j]);
      }
}

// ---------------- flash attention (causal), QBLK=KBLK=64 ----------------
__global__ __launch_bounds__(256) void attn_k(const u16* __restrict__ Qb,
                                              const u16* __restrict__ Kb,
                                              const u16* __restrict__ Vb,
                                              u16* __restrict__ ctx) {
  const float SCALE = 0.03125f;    // 1/sqrt(E)
  int bid = blockIdx.x;
  int qt = bid & 31;               // S/64 = 32 q-tiles
  int bh = bid >> 5;               // 0..15
  int b = bh >> 2, h = bh & 3;
  size_t base = (size_t)bh * SS * DD;
  int q0 = qt * 64;
  int t = threadIdx.x, lane = t & 63, w = t >> 6;
  int lr = lane & 15, kg = lane >> 4;

  __shared__ u16 Ks[64*256];       // K tile  [key][d], rows 512B, swizzled
  __shared__ u16 Vs[256*64];       // V tile transposed [d][key], rows 128B, swizzled
  __shared__ u16 Ps[4][16*64];     // per-wave P tile, rows 128B, swizzled

  // Q fragments stay in registers: wave w owns q rows q0+w*16 .. +15
  bf16x8 qf[8];
  const u16* qp = Qb + base + (size_t)(q0 + w*16 + lr) * DD;
  #pragma unroll
  for (int f = 0; f < 8; ++f) qf[f] = *(const bf16x8*)(qp + f*32 + kg*8);

  f32x4 o[16];
  f32x4 z = {0.f, 0.f, 0.f, 0.f};
  #pragma unroll
  for (int n = 0; n < 16; ++n) o[n] = z;
  float mrun[4] = {-1e30f, -1e30f, -1e30f, -1e30f};
  float lrun[4] = {0.f, 0.f, 0.f, 0.f};

  for (int kt = 0; kt <= qt; ++kt) {
    __syncthreads();
    // stage K [64][256]
    #pragma unroll
    for (int it = 0; it < 8; ++it) {
      int idx = (it*256 + t) * 8;
      int row = idx >> 8, col = idx & 255;
      uint4 d4 = *(const uint4*)(Kb + base + (size_t)(kt*64 + row) * DD + col);
      int bo = (row << 9) + (((col << 1)) ^ ((row & 7) << 4));
      *(uint4*)((char*)Ks + bo) = d4;
    }
    // stage V transposed: Vs[d][key]
    {
      int key = t & 63, dc = t >> 6;
      #pragma unroll
      for (int it = 0; it < 8; ++it) {
        int d0 = dc*8 + it*32;
        union { uint4 u; u16 s[8]; } cv;
        cv.u = *(const uint4*)(Vb + base + (size_t)(kt*64 + key) * DD + d0);
        #pragma unroll
        for (int i = 0; i < 8; ++i) {
          int dd = d0 + i;
          int bo = (dd << 7) + (((key << 1)) ^ ((dd & 7) << 4));
          *(u16*)((char*)Vs + bo) = cv.s[i];
        }
      }
    }
    __syncthreads();

    // S = Q K^T * scale ; per wave 16x64 in 4 16x16 tiles
    f32x4 s[4];
    #pragma unroll
    for (int ct = 0; ct < 4; ++ct) {
      f32x4 a = z;
      #pragma unroll
      for (int dc = 0; dc < 8; ++dc) {
        int row = ct*16 + lr;       // key index in tile
        int bo = (row << 9) + ((((dc << 6) + (kg << 4))) ^ ((row & 7) << 4));
        bf16x8 kb = *(const bf16x8*)((const char*)Ks + bo);
        a = __builtin_amdgcn_mfma_f32_16x16x32_bf16(qf[dc], kb, a, 0, 0, 0);
      }
      #pragma unroll
      for (int j = 0; j < 4; ++j) s[ct][j] = a[j] * SCALE;
    }
    // causal mask on diagonal tile
    if (kt == qt) {
      #pragma unroll
      for (int ct = 0; ct < 4; ++ct) {
        int key_in = ct*16 + lr;
        #pragma unroll
        for (int j = 0; j < 4; ++j) {
          int qrow = w*16 + kg*4 + j;
          if (key_in > qrow) s[ct][j] = -1e9f;
        }
      }
    }
    // online softmax (rows live on 16-lane groups; row = kg*4+j)
    float alpha[4];
    #pragma unroll
    for (int j = 0; j < 4; ++j) {
      float mx = fmaxf(fmaxf(s[0][j], s[1][j]), fmaxf(s[2][j], s[3][j]));
      #pragma unroll
      for (int off = 1; off < 16; off <<= 1) mx = fmaxf(mx, __shfl_xor(mx, off));
      float mnew = fmaxf(mrun[j], mx);
      float al = __expf(mrun[j] - mnew);
      float sum = 0.f;
      #pragma unroll
      for (int ct = 0; ct < 4; ++ct) {
        float p = __expf(s[ct][j] - mnew);
        s[ct][j] = p; sum += p;
      }
      #pragma unroll
      for (int off = 1; off < 16; off <<= 1) sum += __shfl_xor(sum, off);
      lrun[j] = lrun[j] * al + sum;
      mrun[j] = mnew;
      alpha[j] = al;
    }
    #pragma unroll
    for (int n = 0; n < 16; ++n)
      #pragma unroll
      for (int j = 0; j < 4; ++j) o[n][j] *= alpha[j];

    // write P (bf16) to per-wave LDS, reshaped read as A-fragments
    u16* Pw = Ps[w];
    #pragma unroll
    for (int ct = 0; ct < 4; ++ct)
      #pragma unroll
      for (int j = 0; j < 4; ++j) {
        int pr = kg*4 + j, pc = ct*16 + lr;
        int bo = (pr << 7) + (((pc << 1)) ^ ((pr & 7) << 4));
        *(u16*)((char*)Pw + bo) = f2bf(s[ct][j]);
      }
    __syncthreads();   // cross-lane LDS visibility for P (cheap, keeps waves in step)

    // O += P * V
    #pragma unroll
    for (int kk = 0; kk < 2; ++kk) {
      int bo_p = (lr << 7) + ((((kk << 6) + (kg << 4))) ^ ((lr & 7) << 4));
      bf16x8 pa = *(const bf16x8*)((const char*)Pw + bo_p);
      #pragma unroll
      for (int n = 0; n < 16; ++n) {
        int dd = n*16 + lr;
        int bo = (dd << 7) + ((((kk << 6) + (kg << 4))) ^ ((dd & 7) << 4));
        bf16x8 vb = *(const bf16x8*)((const char*)Vs + bo);
        o[n] = __builtin_amdgcn_mfma_f32_16x16x32_bf16(pa, vb, o[n], 0, 0, 0);
      }
    }
  }

  // epilogue: normalize and store ctx[b][s][h*D+d] bf16
  #pragma unroll
  for (int j = 0; j < 4; ++j) lrun[j] = 1.f / lrun[j];
  int srow = q0 + w*16 + kg*4;
  #pragma unroll
  for (int n = 0; n < 16; ++n)
    #pragma unroll
    for (int j = 0; j < 4; ++j) {
      float val = o[n][j] * lrun[j];
      int r = srow + j;
      int c = h*DD + n*16 + lr;
      ctx[(size_t)(b*SS + r) * EE + c] = f2bf(val);
    }
}

// ---------------- output projection + residual ----------------
__global__ __launch_bounds__(256) void proj_gemm_k(const u16* __restrict__ ctx,
                                                   const u16* __restrict__ wot,
                                                   const float* __restrict__ x,
                                                   float* __restrict__ y) {
  __shared__ u16 As[128*64], Bs[128*64];
  int bid = blockIdx.x;                 // 512 = 64 mt x 8 nt
  int mt = bid & 63, nt = bid >> 6;
  f32x4 acc[4][4];
  gemm128(ctx, EE, wot, EE, mt*128, nt*128, EE, As, Bs, acc);
  int t = threadIdx.x, lane = t & 63, w = t >> 6;
  int wr = w >> 1, wc = w & 1, lr = lane & 15, kg = lane >> 4;
  #pragma unroll
  for (int m = 0; m < 4; ++m)
    #pragma unroll
    for (int n = 0; n < 4; ++n)
      #pragma unroll
      for (int j = 0; j < 4; ++j) {
        int r = mt*128 + wr*64 + m*16 + kg*4 + j;
        int c = nt*128 + wc*64 + n*16 + lr;
        size_t idx = (size_t)r * EE + c;
        y[idx] = acc[m][n][j] + x[idx];
      }
}

// ---------------- LayerNorm in-place on y [8192][1024] ----------------
__global__ __launch_bounds__(256) void ln_k(float* __restrict__ y,
                                            const float* __restrict__ gamma,
                                            const float* __restrict__ beta) {
  int row = blockIdx.x;
  int t = threadIdx.x;
  float4 v = *((const float4*)(y + (size_t)row * EE) + t);
  float s = v.x + v.y + v.z + v.w;
  float ss = v.x*v.x + v.y*v.y + v.z*v.z + v.w*v.w;
  #pragma unroll
  for (int off = 1; off < 64; off <<= 1) {
    s  += __shfl_xor(s, off);
    ss += __shfl_xor(ss, off);
  }
  __shared__ float rs[4], rss[4];
  int w = t >> 6, lane = t & 63;
  if (lane == 0) { rs[w] = s; rss[w] = ss; }
  __syncthreads();
  s  = rs[0] + rs[1] + rs[2] + rs[3];
  ss = rss[0] + rss[1] + rss[2] + rss[3];
  float mean = s * (1.f / EE);
  float var  = ss * (1.f / EE) - mean * mean;
  float rstd = rsqrtf(var + 1e-6f);
  float4 g  = *((const float4*)gamma + t);
  float4 be = *((const float4*)beta + t);
  float4 ov;
  ov.x = (v.x - mean) * rstd * g.x + be.x;
  ov.y = (v.y - mean) * rstd * g.y + be.y;
  ov.z = (v.z - mean) * rstd * g.z + be.z;
  ov.w = (v.w - mean) * rstd * g.w + be.w;
  *((float4*)(y + (size_t)row * EE) + t) = ov;
}

extern "C" void kernel_launch(void* const* d_in, const int* in_sizes, int n_in,
                              void* d_out, int out_size, void* d_ws, size_t ws_size,
                              hipStream_t stream) {
  const float* x      = (const float*)d_in[0];
  const float* qkv_w  = (const float*)d_in[1];
  const float* out_w  = (const float*)d_in[2];
  const float* gamma  = (const float*)d_in[3];
  const float* beta   = (const float*)d_in[4];
  float* out = (float*)d_out;
  char* ws = (char*)d_ws;

  // ws layout (bytes); ctx aliases xb (xb dead after QKV GEMM)
  u16* xb  = (u16*)(ws);                       // 8192*1024       (16.78 MB)
  u16* ctx = xb;                               // [8192][1024] bf16 (reuse)
  u16* wqt = (u16*)(ws + 16777216);            // [12][256][1024] ( 6.29 MB)
  u16* wot = (u16*)(ws + 23068672);            // [1024][1024]    ( 2.10 MB)
  u16* Qb  = (u16*)(ws + 25165824);            // [B][H][S][D] x3 (50.33 MB)
  u16* Kb  = Qb + (size_t)BB*HH*SS*DD;
  u16* Vb  = Kb + (size_t)BB*HH*SS*DD;

  // 1) casts / transposes
  cast_bf16_k<<<8192, 256, 0, stream>>>(x, xb, (BB*SS*EE)/4);
  transpose_cast_k<<<dim3(8, 32, 12), dim3(32, 8), 0, stream>>>(qkv_w, wqt, EE, DD);
  transpose_cast_k<<<dim3(32, 32, 1), dim3(32, 8), 0, stream>>>(out_w, wot, EE, EE);
  // 2) QKV projection: 12 * (8192x256x1024)
  qkv_gemm_k<<<1536, 256, 0, stream>>>(xb, wqt, Qb);
  // 3) causal flash attention
  attn_k<<<512, 256, 0, stream>>>(Qb, Kb, Vb, ctx);
  // 4) output projection + residual -> d_out (f32)
  proj_gemm_k<<<512, 256, 0, stream>>>(ctx, wot, x, out);
  // 5) LayerNorm in place
  ln_k<<<8192, 256, 0, stream>>>(out, gamma, beta);
}

// Round 2
// 320.176 us; speedup vs baseline: 1.1167x; 1.1167x over previous
//
#include <hip/hip_runtime.h>

typedef __attribute__((ext_vector_type(8))) __bf16 bf16x8;
typedef __attribute__((ext_vector_type(4))) float f32x4;
typedef unsigned short u16;
typedef unsigned int u32;

#define BB 4
#define SS 2048
#define EE 1024
#define HH 4
#define DD 256

#define GLOAD_LDS(g, l) __builtin_amdgcn_global_load_lds( \
    (const __attribute__((address_space(1))) unsigned int*)(g), \
    (__attribute__((address_space(3))) unsigned int*)(l), 16, 0, 0)

__device__ __forceinline__ u16 f2bf(float f) {
  unsigned int u = __float_as_uint(f);
  u = (u + 0x7FFFu + ((u >> 16) & 1u)) >> 16;   // RNE
  return (u16)u;
}

// ---------------- cast f32 -> bf16 (vectorized) ----------------
__global__ __launch_bounds__(256) void cast_bf16_k(const float* __restrict__ in,
                                                   u16* __restrict__ out, int n4) {
  int i = blockIdx.x * 256 + threadIdx.x;
  if (i >= n4) return;
  float4 v = ((const float4*)in)[i];
  union { u16 s[4]; uint2 u; } o;
  o.s[0] = f2bf(v.x); o.s[1] = f2bf(v.y); o.s[2] = f2bf(v.z); o.s[3] = f2bf(v.w);
  ((uint2*)out)[i] = o.u;
}

// ---------------- transpose + cast: in[R][C] f32 -> out[C][R] bf16 ----------------
__global__ __launch_bounds__(256) void transpose_cast_k(const float* __restrict__ in,
                                                        u16* __restrict__ out, int R, int C) {
  __shared__ float tile[32][33];
  size_t moff = (size_t)blockIdx.z * R * C;
  in += moff; out += moff;
  int c0 = blockIdx.x * 32, r0 = blockIdx.y * 32;
  int tx = threadIdx.x, ty = threadIdx.y;   // 32 x 8
  #pragma unroll
  for (int i = 0; i < 4; ++i)
    tile[ty + 8*i][tx] = in[(size_t)(r0 + ty + 8*i) * C + c0 + tx];
  __syncthreads();
  #pragma unroll
  for (int i = 0; i < 4; ++i)
    out[(size_t)(c0 + ty + 8*i) * R + r0 + tx] = f2bf(tile[tx][ty + 8*i]);
}

// ---------------- 128x128 bf16 GEMM core: C = A[M][K] * Bt[N][K]^T ----------------
// 4 waves 2x2, each 64x64 (4x4 16x16 frags). BK=64. global_load_lds with
// pre-swizzled source (LDS linear dest, swizzled-content convention).
__device__ __forceinline__ void gemm128(const u16* __restrict__ A, int lda,
                                        const u16* __restrict__ Bt, int ldb,
                                        int row0, int col0, int K,
                                        u16* As, u16* Bs, f32x4 acc[4][4]) {
  int t = threadIdx.x;
  int lane = t & 63, w = t >> 6;
  int wr = w >> 1, wc = w & 1;
  int lr = lane & 15, kg = lane >> 4;
  f32x4 z = {0.f, 0.f, 0.f, 0.f};
  #pragma unroll
  for (int m = 0; m < 4; ++m)
    #pragma unroll
    for (int n = 0; n < 4; ++n) acc[m][n] = z;
  for (int kt = 0; kt < K; kt += 64) {
    __syncthreads();
    #pragma unroll
    for (int it = 0; it < 4; ++it) {
      int Lb = it*4096 + w*1024 + lane*16;       // dest byte within 128x64 tile
      int row = Lb >> 7;
      int scb = ((Lb >> 4) & 7) ^ (row & 7);     // pre-swizzled source col-block
      GLOAD_LDS(A  + (size_t)(row0 + row) * lda + kt + scb*8,
                (char*)As + it*4096 + w*1024);
      GLOAD_LDS(Bt + (size_t)(col0 + row) * ldb + kt + scb*8,
                (char*)Bs + it*4096 + w*1024);
    }
    __syncthreads();
    __builtin_amdgcn_s_setprio(1);
    #pragma unroll
    for (int kk = 0; kk < 2; ++kk) {
      bf16x8 af[4], bfr[4];
      #pragma unroll
      for (int m = 0; m < 4; ++m) {
        int row = wr*64 + m*16 + lr;
        int bo = (row << 7) + ((((kk << 6) + (kg << 4))) ^ ((row & 7) << 4));
        af[m] = *(const bf16x8*)((const char*)As + bo);
      }
      #pragma unroll
      for (int n = 0; n < 4; ++n) {
        int row = wc*64 + n*16 + lr;
        int bo = (row << 7) + ((((kk << 6) + (kg << 4))) ^ ((row & 7) << 4));
        bfr[n] = *(const bf16x8*)((const char*)Bs + bo);
      }
      #pragma unroll
      for (int m = 0; m < 4; ++m)
        #pragma unroll
        for (int n = 0; n < 4; ++n)
          acc[m][n] = __builtin_amdgcn_mfma_f32_16x16x32_bf16(af[m], bfr[n], acc[m][n], 0, 0, 0);
    }
    __builtin_amdgcn_s_setprio(0);
  }
}

// ---------------- QKV projection ----------------
__global__ __launch_bounds__(256) void qkv_gemm_k(const u16* __restrict__ xb,
                                                  const u16* __restrict__ wt,
                                                  u16* __restrict__ qkv) {
  __shared__ u16 As[128*64], Bs[128*64];
  int bid = blockIdx.x;
  int mh = bid >> 7;               // 0..11  (qkvi*4 + h)
  int tt = bid & 127;
  int mt = tt & 63, nt = tt >> 6;  // 64 M-tiles, 2 N-tiles
  f32x4 acc[4][4];
  gemm128(xb, EE, wt + (size_t)mh * DD * EE, EE, mt*128, nt*128, EE, As, Bs, acc);
  int t = threadIdx.x, lane = t & 63, w = t >> 6;
  int wr = w >> 1, wc = w & 1, lr = lane & 15, kg = lane >> 4;
  int qi = mh >> 2, h = mh & 3;
  u16* outp = qkv + (size_t)qi * (BB*HH*SS*DD);
  #pragma unroll
  for (int m = 0; m < 4; ++m)
    #pragma unroll
    for (int n = 0; n < 4; ++n)
      #pragma unroll
      for (int j = 0; j < 4; ++j) {
        int r = mt*128 + wr*64 + m*16 + kg*4 + j;   // global row = b*2048+s
        int c = nt*128 + wc*64 + n*16 + lr;         // d
        int b = r >> 11, s = r & 2047;
        outp[(size_t)((b*HH + h) * SS + s) * DD + c] = f2bf(acc[m][n][j]);
      }
}

// ---------------- flash attention (causal), QBLK=KBLK=64 ----------------
// Register-prefetched K/V staging (T14), vectorized V transpose, 2 barriers/iter.
__global__ __launch_bounds__(256, 2) void attn_k(const u16* __restrict__ Qb,
                                                 const u16* __restrict__ Kb,
                                                 const u16* __restrict__ Vb,
                                                 u16* __restrict__ ctx) {
  const float SCALE = 0.03125f;    // 1/sqrt(E)
  int bid = blockIdx.x;
  int qt = bid & 31;               // S/64 = 32 q-tiles
  int bh = bid >> 5;               // 0..15
  int b = bh >> 2, h = bh & 3;
  size_t base = (size_t)bh * SS * DD;
  int q0 = qt * 64;
  int t = threadIdx.x, lane = t & 63, w = t >> 6;
  int lr = lane & 15, kg = lane >> 4;
  int kq = t & 15, dgrp = t >> 4;  // V-staging role

  __shared__ u16 Ks[64*256];       // K tile  [key][d], rows 512B, swizzled
  __shared__ u16 Vs[256*64];       // V tile transposed [d][key], rows 128B, swizzled
  __shared__ u16 Ps[4][16*64];     // per-wave P tile, rows 128B, swizzled

  // Q fragments stay in registers: wave w owns q rows q0+w*16 .. +15
  bf16x8 qf[8];
  const u16* qp = Qb + base + (size_t)(q0 + w*16 + lr) * DD;
  #pragma unroll
  for (int f = 0; f < 8; ++f) qf[f] = *(const bf16x8*)(qp + f*32 + kg*8);

  f32x4 o[16];
  f32x4 z = {0.f, 0.f, 0.f, 0.f};
  #pragma unroll
  for (int n = 0; n < 16; ++n) o[n] = z;
  float mrun[4] = {-1e30f, -1e30f, -1e30f, -1e30f};
  float lrun[4] = {0.f, 0.f, 0.f, 0.f};

  uint4 kreg[8], vreg[8];
  // prologue: load tile 0 into registers
  #pragma unroll
  for (int it = 0; it < 8; ++it) {
    int idx = (it*256 + t) * 8;
    int row = idx >> 8, col = idx & 255;
    kreg[it] = *(const uint4*)(Kb + base + (size_t)row * DD + col);
  }
  #pragma unroll
  for (int j = 0; j < 4; ++j)
    #pragma unroll
    for (int hh = 0; hh < 2; ++hh)
      vreg[j*2 + hh] = *(const uint4*)(Vb + base + (size_t)(kq*4 + j) * DD + dgrp*16 + hh*8);

  for (int kt = 0; kt <= qt; ++kt) {
    __syncthreads();                 // all waves done reading prev K/V tiles
    // ---- write staged registers to LDS ----
    #pragma unroll
    for (int it = 0; it < 8; ++it) {
      int idx = (it*256 + t) * 8;
      int row = idx >> 8, col = idx & 255;
      int bo = (row << 9) + (((col << 1)) ^ ((row & 7) << 4));
      *(uint4*)((char*)Ks + bo) = kreg[it];
    }
    #pragma unroll
    for (int hh = 0; hh < 2; ++hh)
      #pragma unroll
      for (int i = 0; i < 8; ++i) {
        int dd = dgrp*16 + hh*8 + i;
        u32 w0 = ((const u32*)&vreg[0 + hh])[i >> 1];
        u32 w1 = ((const u32*)&vreg[2 + hh])[i >> 1];
        u32 w2 = ((const u32*)&vreg[4 + hh])[i >> 1];
        u32 w3 = ((const u32*)&vreg[6 + hh])[i >> 1];
        u32 e0 = (i & 1) ? (w0 >> 16) : (w0 & 0xffffu);
        u32 e1 = (i & 1) ? (w1 & 0xffff0000u) : (w1 << 16);
        u32 e2 = (i & 1) ? (w2 >> 16) : (w2 & 0xffffu);
        u32 e3 = (i & 1) ? (w3 & 0xffff0000u) : (w3 << 16);
        uint2 pk; pk.x = e0 | e1; pk.y = e2 | e3;
        int bo = (dd << 7) + (((kq << 3)) ^ ((dd & 7) << 4));
        *(uint2*)((char*)Vs + bo) = pk;
      }
    __syncthreads();                 // staged tile visible

    // ---- issue prefetch for next tile (latency hides under compute) ----
    if (kt < qt) {
      int kt1 = kt + 1;
      #pragma unroll
      for (int it = 0; it < 8; ++it) {
        int idx = (it*256 + t) * 8;
        int row = idx >> 8, col = idx & 255;
        kreg[it] = *(const uint4*)(Kb + base + (size_t)(kt1*64 + row) * DD + col);
      }
      #pragma unroll
      for (int j = 0; j < 4; ++j)
        #pragma unroll
        for (int hh = 0; hh < 2; ++hh)
          vreg[j*2 + hh] = *(const uint4*)(Vb + base + (size_t)(kt1*64 + kq*4 + j) * DD + dgrp*16 + hh*8);
    }

    // ---- S = Q K^T * scale ; per wave 16x64 in 4 16x16 tiles ----
    f32x4 s[4];
    __builtin_amdgcn_s_setprio(1);
    #pragma unroll
    for (int ct = 0; ct < 4; ++ct) {
      f32x4 a = z;
      #pragma unroll
      for (int dc = 0; dc < 8; ++dc) {
        int row = ct*16 + lr;       // key index in tile
        int bo = (row << 9) + ((((dc << 6) + (kg << 4))) ^ ((row & 7) << 4));
        bf16x8 kb = *(const bf16x8*)((const char*)Ks + bo);
        a = __builtin_amdgcn_mfma_f32_16x16x32_bf16(qf[dc], kb, a, 0, 0, 0);
      }
      #pragma unroll
      for (int j = 0; j < 4; ++j) s[ct][j] = a[j] * SCALE;
    }
    __builtin_amdgcn_s_setprio(0);
    // causal mask on diagonal tile
    if (kt == qt) {
      #pragma unroll
      for (int ct = 0; ct < 4; ++ct) {
        int key_in = ct*16 + lr;
        #pragma unroll
        for (int j = 0; j < 4; ++j) {
          int qrow = w*16 + kg*4 + j;
          if (key_in > qrow) s[ct][j] = -1e9f;
        }
      }
    }
    // ---- online softmax (row = kg*4+j across 16-lane groups) ----
    float alpha[4];
    #pragma unroll
    for (int j = 0; j < 4; ++j) {
      float mx = fmaxf(fmaxf(s[0][j], s[1][j]), fmaxf(s[2][j], s[3][j]));
      #pragma unroll
      for (int off = 1; off < 16; off <<= 1) mx = fmaxf(mx, __shfl_xor(mx, off));
      float mnew = fmaxf(mrun[j], mx);
      float al = __expf(mrun[j] - mnew);
      float sum = 0.f;
      #pragma unroll
      for (int ct = 0; ct < 4; ++ct) {
        float p = __expf(s[ct][j] - mnew);
        s[ct][j] = p; sum += p;
      }
      #pragma unroll
      for (int off = 1; off < 16; off <<= 1) sum += __shfl_xor(sum, off);
      lrun[j] = lrun[j] * al + sum;
      mrun[j] = mnew;
      alpha[j] = al;
    }
    #pragma unroll
    for (int n = 0; n < 16; ++n)
      #pragma unroll
      for (int j = 0; j < 4; ++j) o[n][j] *= alpha[j];

    // ---- P -> per-wave LDS (no barrier needed: wave-private buffer) ----
    u16* Pw = Ps[w];
    #pragma unroll
    for (int ct = 0; ct < 4; ++ct)
      #pragma unroll
      for (int j = 0; j < 4; ++j) {
        int pr = kg*4 + j, pc = ct*16 + lr;
        int bo = (pr << 7) + (((pc << 1)) ^ ((pr & 7) << 4));
        *(u16*)((char*)Pw + bo) = f2bf(s[ct][j]);
      }

    // ---- O += P * V ----
    __builtin_amdgcn_s_setprio(1);
    #pragma unroll
    for (int kk = 0; kk < 2; ++kk) {
      int bo_p = (lr << 7) + ((((kk << 6) + (kg << 4))) ^ ((lr & 7) << 4));
      bf16x8 pa = *(const bf16x8*)((const char*)Pw + bo_p);
      #pragma unroll
      for (int n = 0; n < 16; ++n) {
        int dd = n*16 + lr;
        int bo = (dd << 7) + ((((kk << 6) + (kg << 4))) ^ ((dd & 7) << 4));
        bf16x8 vb = *(const bf16x8*)((const char*)Vs + bo);
        o[n] = __builtin_amdgcn_mfma_f32_16x16x32_bf16(pa, vb, o[n], 0, 0, 0);
      }
    }
    __builtin_amdgcn_s_setprio(0);
  }

  // epilogue: normalize and store ctx[b][s][h*D+d] bf16
  #pragma unroll
  for (int j = 0; j < 4; ++j) lrun[j] = 1.f / lrun[j];
  int srow = q0 + w*16 + kg*4;
  #pragma unroll
  for (int n = 0; n < 16; ++n)
    #pragma unroll
    for (int j = 0; j < 4; ++j) {
      float val = o[n][j] * lrun[j];
      int r = srow + j;
      int c = h*DD + n*16 + lr;
      ctx[(size_t)(b*SS + r) * EE + c] = f2bf(val);
    }
}

// ---------------- output projection + residual ----------------
__global__ __launch_bounds__(256) void proj_gemm_k(const u16* __restrict__ ctx,
                                                   const u16* __restrict__ wot,
                                                   const float* __restrict__ x,
                                                   float* __restrict__ y) {
  __shared__ u16 As[128*64], Bs[128*64];
  int bid = blockIdx.x;                 // 512 = 64 mt x 8 nt
  int mt = bid & 63, nt = bid >> 6;
  f32x4 acc[4][4];
  gemm128(ctx, EE, wot, EE, mt*128, nt*128, EE, As, Bs, acc);
  int t = threadIdx.x, lane = t & 63, w = t >> 6;
  int wr = w >> 1, wc = w & 1, lr = lane & 15, kg = lane >> 4;
  #pragma unroll
  for (int m = 0; m < 4; ++m)
    #pragma unroll
    for (int n = 0; n < 4; ++n)
      #pragma unroll
      for (int j = 0; j < 4; ++j) {
        int r = mt*128 + wr*64 + m*16 + kg*4 + j;
        int c = nt*128 + wc*64 + n*16 + lr;
        size_t idx = (size_t)r * EE + c;
        y[idx] = acc[m][n][j] + x[idx];
      }
}

// ---------------- LayerNorm in-place on y [8192][1024] ----------------
__global__ __launch_bounds__(256) void ln_k(float* __restrict__ y,
                                            const float* __restrict__ gamma,
                                            const float* __restrict__ beta) {
  int row = blockIdx.x;
  int t = threadIdx.x;
  float4 v = *((const float4*)(y + (size_t)row * EE) + t);
  float s = v.x + v.y + v.z + v.w;
  float ss = v.x*v.x + v.y*v.y + v.z*v.z + v.w*v.w;
  #pragma unroll
  for (int off = 1; off < 64; off <<= 1) {
    s  += __shfl_xor(s, off);
    ss += __shfl_xor(ss, off);
  }
  __shared__ float rs[4], rss[4];
  int w = t >> 6, lane = t & 63;
  if (lane == 0) { rs[w] = s; rss[w] = ss; }
  __syncthreads();
  s  = rs[0] + rs[1] + rs[2] + rs[3];
  ss = rss[0] + rss[1] + rss[2] + rss[3];
  float mean = s * (1.f / EE);
  float var  = ss * (1.f / EE) - mean * mean;
  float rstd = rsqrtf(var + 1e-6f);
  float4 g  = *((const float4*)gamma + t);
  float4 be = *((const float4*)beta + t);
  float4 ov;
  ov.x = (v.x - mean) * rstd * g.x + be.x;
  ov.y = (v.y - mean) * rstd * g.y + be.y;
  ov.z = (v.z - mean) * rstd * g.z + be.z;
  ov.w = (v.w - mean) * rstd * g.w + be.w;
  *((float4*)(y + (size_t)row * EE) + t) = ov;
}

extern "C" void kernel_launch(void* const* d_in, const int* in_sizes, int n_in,
                              void* d_out, int out_size, void* d_ws, size_t ws_size,
                              hipStream_t stream) {
  const float* x      = (const float*)d_in[0];
  const float* qkv_w  = (const float*)d_in[1];
  const float* out_w  = (const float*)d_in[2];
  const float* gamma  = (const float*)d_in[3];
  const float* beta   = (const float*)d_in[4];
  float* out = (float*)d_out;
  char* ws = (char*)d_ws;

  // ws layout (bytes); ctx aliases xb (xb dead after QKV GEMM)
  u16* xb  = (u16*)(ws);                       // 8192*1024       (16.78 MB)
  u16* ctx = xb;                               // [8192][1024] bf16 (reuse)
  u16* wqt = (u16*)(ws + 16777216);            // [12][256][1024] ( 6.29 MB)
  u16* wot = (u16*)(ws + 23068672);            // [1024][1024]    ( 2.10 MB)
  u16* Qb  = (u16*)(ws + 25165824);            // [B][H][S][D] x3 (50.33 MB)
  u16* Kb  = Qb + (size_t)BB*HH*SS*DD;
  u16* Vb  = Kb + (size_t)BB*HH*SS*DD;

  // 1) casts / transposes
  cast_bf16_k<<<8192, 256, 0, stream>>>(x, xb, (BB*SS*EE)/4);
  transpose_cast_k<<<dim3(8, 32, 12), dim3(32, 8), 0, stream>>>(qkv_w, wqt, EE, DD);
  transpose_cast_k<<<dim3(32, 32, 1), dim3(32, 8), 0, stream>>>(out_w, wot, EE, EE);
  // 2) QKV projection: 12 * (8192x256x1024)
  qkv_gemm_k<<<1536, 256, 0, stream>>>(xb, wqt, Qb);
  // 3) causal flash attention
  attn_k<<<512, 256, 0, stream>>>(Qb, Kb, Vb, ctx);
  // 4) output projection + residual -> d_out (f32)
  proj_gemm_k<<<512, 256, 0, stream>>>(ctx, wot, x, out);
  // 5) LayerNorm in place
  ln_k<<<8192, 256, 0, stream>>>(out, gamma, beta);
}

// Round 3
// 246.869 us; speedup vs baseline: 1.4483x; 1.2969x over previous
//
#include <hip/hip_runtime.h>

typedef __attribute__((ext_vector_type(8))) __bf16 bf16x8;
typedef __attribute__((ext_vector_type(4))) float f32x4;
typedef unsigned short u16;
typedef unsigned int u32;

#define BB 4
#define SS 2048
#define EE 1024
#define HH 4
#define DD 256

#define GLOAD_LDS(g, l) __builtin_amdgcn_global_load_lds( \
    (const __attribute__((address_space(1))) unsigned int*)(g), \
    (__attribute__((address_space(3))) unsigned int*)(l), 16, 0, 0)

__device__ __forceinline__ u16 f2bf(float f) {
  unsigned int u = __float_as_uint(f);
  u = (u + 0x7FFFu + ((u >> 16) & 1u)) >> 16;   // RNE
  return (u16)u;
}

// ---------------- cast f32 -> bf16 (vectorized) ----------------
__global__ __launch_bounds__(256) void cast_bf16_k(const float* __restrict__ in,
                                                   u16* __restrict__ out, int n4) {
  int i = blockIdx.x * 256 + threadIdx.x;
  if (i >= n4) return;
  float4 v = ((const float4*)in)[i];
  union { u16 s[4]; uint2 u; } o;
  o.s[0] = f2bf(v.x); o.s[1] = f2bf(v.y); o.s[2] = f2bf(v.z); o.s[3] = f2bf(v.w);
  ((uint2*)out)[i] = o.u;
}

// ---------------- transpose + cast: in[R][C] f32 -> out[C][R] bf16 ----------------
__global__ __launch_bounds__(256) void transpose_cast_k(const float* __restrict__ in,
                                                        u16* __restrict__ out, int R, int C) {
  __shared__ float tile[32][33];
  size_t moff = (size_t)blockIdx.z * R * C;
  in += moff; out += moff;
  int c0 = blockIdx.x * 32, r0 = blockIdx.y * 32;
  int tx = threadIdx.x, ty = threadIdx.y;   // 32 x 8
  #pragma unroll
  for (int i = 0; i < 4; ++i)
    tile[ty + 8*i][tx] = in[(size_t)(r0 + ty + 8*i) * C + c0 + tx];
  __syncthreads();
  #pragma unroll
  for (int i = 0; i < 4; ++i)
    out[(size_t)(c0 + ty + 8*i) * R + r0 + tx] = f2bf(tile[tx][ty + 8*i]);
}

// ---------------- 128x128 bf16 GEMM core: C = A[M][K] * Bt[N][K]^T ----------------
__device__ __forceinline__ void gemm128(const u16* __restrict__ A, int lda,
                                        const u16* __restrict__ Bt, int ldb,
                                        int row0, int col0, int K,
                                        u16* As, u16* Bs, f32x4 acc[4][4]) {
  int t = threadIdx.x;
  int lane = t & 63, w = t >> 6;
  int wr = w >> 1, wc = w & 1;
  int lr = lane & 15, kg = lane >> 4;
  f32x4 z = {0.f, 0.f, 0.f, 0.f};
  #pragma unroll
  for (int m = 0; m < 4; ++m)
    #pragma unroll
    for (int n = 0; n < 4; ++n) acc[m][n] = z;
  for (int kt = 0; kt < K; kt += 64) {
    __syncthreads();
    #pragma unroll
    for (int it = 0; it < 4; ++it) {
      int Lb = it*4096 + w*1024 + lane*16;       // dest byte within 128x64 tile
      int row = Lb >> 7;
      int scb = ((Lb >> 4) & 7) ^ (row & 7);     // pre-swizzled source col-block
      GLOAD_LDS(A  + (size_t)(row0 + row) * lda + kt + scb*8,
                (char*)As + it*4096 + w*1024);
      GLOAD_LDS(Bt + (size_t)(col0 + row) * ldb + kt + scb*8,
                (char*)Bs + it*4096 + w*1024);
    }
    __syncthreads();
    __builtin_amdgcn_s_setprio(1);
    #pragma unroll
    for (int kk = 0; kk < 2; ++kk) {
      bf16x8 af[4], bfr[4];
      #pragma unroll
      for (int m = 0; m < 4; ++m) {
        int row = wr*64 + m*16 + lr;
        int bo = (row << 7) + ((((kk << 6) + (kg << 4))) ^ ((row & 7) << 4));
        af[m] = *(const bf16x8*)((const char*)As + bo);
      }
      #pragma unroll
      for (int n = 0; n < 4; ++n) {
        int row = wc*64 + n*16 + lr;
        int bo = (row << 7) + ((((kk << 6) + (kg << 4))) ^ ((row & 7) << 4));
        bfr[n] = *(const bf16x8*)((const char*)Bs + bo);
      }
      #pragma unroll
      for (int m = 0; m < 4; ++m)
        #pragma unroll
        for (int n = 0; n < 4; ++n)
          acc[m][n] = __builtin_amdgcn_mfma_f32_16x16x32_bf16(af[m], bfr[n], acc[m][n], 0, 0, 0);
    }
    __builtin_amdgcn_s_setprio(0);
  }
}

// ---------------- QKV projection ----------------
__global__ __launch_bounds__(256) void qkv_gemm_k(const u16* __restrict__ xb,
                                                  const u16* __restrict__ wt,
                                                  u16* __restrict__ qkv) {
  __shared__ u16 As[128*64], Bs[128*64];
  int bid = blockIdx.x;
  int mh = bid >> 7;               // 0..11  (qkvi*4 + h)
  int tt = bid & 127;
  int mt = tt & 63, nt = tt >> 6;  // 64 M-tiles, 2 N-tiles
  f32x4 acc[4][4];
  gemm128(xb, EE, wt + (size_t)mh * DD * EE, EE, mt*128, nt*128, EE, As, Bs, acc);
  int t = threadIdx.x, lane = t & 63, w = t >> 6;
  int wr = w >> 1, wc = w & 1, lr = lane & 15, kg = lane >> 4;
  int qi = mh >> 2, h = mh & 3;
  u16* outp = qkv + (size_t)qi * (BB*HH*SS*DD);
  #pragma unroll
  for (int m = 0; m < 4; ++m)
    #pragma unroll
    for (int n = 0; n < 4; ++n)
      #pragma unroll
      for (int j = 0; j < 4; ++j) {
        int r = mt*128 + wr*64 + m*16 + kg*4 + j;   // global row = b*2048+s
        int c = nt*128 + wc*64 + n*16 + lr;         // d
        int b = r >> 11, s = r & 2047;
        outp[(size_t)((b*HH + h) * SS + s) * DD + c] = f2bf(acc[m][n][j]);
      }
}

// ---------------- flash attention (causal), paired q-tiles ----------------
// 8 waves: waves 0-3 -> tile qtA=31-p (heavy), waves 4-7 -> tile qtB=p (light).
// Shared K/V staging; XCD-chunked bh mapping for L2 locality.
__global__ __launch_bounds__(512, 1) void attn_k(const u16* __restrict__ Qb,
                                                 const u16* __restrict__ Kb,
                                                 const u16* __restrict__ Vb,
                                                 u16* __restrict__ ctx) {
  const float SCALE = 0.03125f;    // 1/sqrt(E)
  int bid = blockIdx.x;            // 256 blocks
  int xcd = bid & 7, slot = bid >> 3;      // xcd gets bh {2*xcd, 2*xcd+1}
  int bh = xcd*2 + (slot >> 4);
  int p  = slot & 15;
  int qtA = 31 - p, qtB = p;       // qtA >= 16 > qtB
  int b = bh >> 2, h = bh & 3;
  size_t base = (size_t)bh * SS * DD;
  int t = threadIdx.x, lane = t & 63, w = t >> 6;
  int grp = w >> 2, wl = w & 3;
  int qt = grp ? qtB : qtA;
  int q0 = qt * 64;
  int kvmax = qtA;
  int lr = lane & 15, kg = lane >> 4;
  int kq = t & 15, dgrp = t >> 4;  // V staging role (dgrp 0..31 -> 8 d each)

  __shared__ u16 Ks[64*256];       // K tile  [key][d], rows 512B, swizzled
  __shared__ u16 Vs[256*64];       // V tile transposed [d][key], rows 128B, swizzled
  __shared__ u16 Ps[8][16*64];     // per-wave P tile

  // Q fragments: wave handles q rows q0 + wl*16 .. +15
  bf16x8 qf[8];
  const u16* qp = Qb + base + (size_t)(q0 + wl*16 + lr) * DD;
  #pragma unroll
  for (int f = 0; f < 8; ++f) qf[f] = *(const bf16x8*)(qp + f*32 + kg*8);

  f32x4 o[16];
  f32x4 z = {0.f, 0.f, 0.f, 0.f};
  #pragma unroll
  for (int n = 0; n < 16; ++n) o[n] = z;
  float mrun[4] = {-1e30f, -1e30f, -1e30f, -1e30f};
  float lrun[4] = {0.f, 0.f, 0.f, 0.f};

  uint4 kreg[4], vreg[4];
  // prologue: load tile 0
  #pragma unroll
  for (int it = 0; it < 4; ++it) {
    int row = it*16 + (t >> 5), col = (t & 31) * 8;
    kreg[it] = *(const uint4*)(Kb + base + (size_t)row * DD + col);
  }
  #pragma unroll
  for (int j = 0; j < 4; ++j)
    vreg[j] = *(const uint4*)(Vb + base + (size_t)(kq*4 + j) * DD + dgrp*8);

  for (int kt = 0; kt <= kvmax; ++kt) {
    __syncthreads();                 // all waves done reading prev K/V
    // ---- write staged K ----
    #pragma unroll
    for (int it = 0; it < 4; ++it) {
      int row = it*16 + (t >> 5), col = (t & 31) * 8;
      int bo = (row << 9) + (((col << 1)) ^ ((row & 7) << 4));
      *(uint4*)((char*)Ks + bo) = kreg[it];
    }
    // ---- write staged V transposed (v_perm pack) ----
    #pragma unroll
    for (int i = 0; i < 8; ++i) {
      int dd = dgrp*8 + i;
      u32 w0 = ((const u32*)&vreg[0])[i >> 1];
      u32 w1 = ((const u32*)&vreg[1])[i >> 1];
      u32 w2 = ((const u32*)&vreg[2])[i >> 1];
      u32 w3 = ((const u32*)&vreg[3])[i >> 1];
      u32 sel = (i & 1) ? 0x07060302u : 0x05040100u;
      uint2 pk;
      pk.x = __builtin_amdgcn_perm(w1, w0, sel);
      pk.y = __builtin_amdgcn_perm(w3, w2, sel);
      int bo = (dd << 7) + (((kq << 3)) ^ ((dd & 7) << 4));
      *(uint2*)((char*)Vs + bo) = pk;
    }
    __syncthreads();                 // staged tile visible

    // ---- prefetch next tile ----
    if (kt < kvmax) {
      int kt1 = kt + 1;
      #pragma unroll
      for (int it = 0; it < 4; ++it) {
        int row = it*16 + (t >> 5), col = (t & 31) * 8;
        kreg[it] = *(const uint4*)(Kb + base + (size_t)(kt1*64 + row) * DD + col);
      }
      #pragma unroll
      for (int j = 0; j < 4; ++j)
        vreg[j] = *(const uint4*)(Vb + base + (size_t)(kt1*64 + kq*4 + j) * DD + dgrp*8);
    }

    if (kt <= qt) {                  // wave-uniform: this group's tile still active
      // ---- S = Q K^T * scale ----
      f32x4 s[4];
      __builtin_amdgcn_s_setprio(1);
      #pragma unroll
      for (int ct = 0; ct < 4; ++ct) {
        f32x4 a = z;
        #pragma unroll
        for (int dc = 0; dc < 8; ++dc) {
          int row = ct*16 + lr;
          int bo = (row << 9) + ((((dc << 6) + (kg << 4))) ^ ((row & 7) << 4));
          bf16x8 kb = *(const bf16x8*)((const char*)Ks + bo);
          a = __builtin_amdgcn_mfma_f32_16x16x32_bf16(qf[dc], kb, a, 0, 0, 0);
        }
        #pragma unroll
        for (int j = 0; j < 4; ++j) s[ct][j] = a[j] * SCALE;
      }
      __builtin_amdgcn_s_setprio(0);
      // causal mask on diagonal tile
      if (kt == qt) {
        #pragma unroll
        for (int ct = 0; ct < 4; ++ct) {
          int key_in = ct*16 + lr;
          #pragma unroll
          for (int j = 0; j < 4; ++j) {
            int qrow = wl*16 + kg*4 + j;
            if (key_in > qrow) s[ct][j] = -1e9f;
          }
        }
      }
      // ---- online softmax (row = kg*4+j across 16-lane groups) ----
      float alpha[4];
      bool need_rescale = false;
      #pragma unroll
      for (int j = 0; j < 4; ++j) {
        float mx = fmaxf(fmaxf(s[0][j], s[1][j]), fmaxf(s[2][j], s[3][j]));
        #pragma unroll
        for (int off = 1; off < 16; off <<= 1) mx = fmaxf(mx, __shfl_xor(mx, off));
        float mnew = fmaxf(mrun[j], mx);
        float al = __expf(mrun[j] - mnew);
        float sum = 0.f;
        #pragma unroll
        for (int ct = 0; ct < 4; ++ct) {
          float pv = __expf(s[ct][j] - mnew);
          s[ct][j] = pv; sum += pv;
        }
        #pragma unroll
        for (int off = 1; off < 16; off <<= 1) sum += __shfl_xor(sum, off);
        lrun[j] = lrun[j] * al + sum;
        mrun[j] = mnew;
        alpha[j] = al;
        if (al != 1.0f) need_rescale = true;
      }
      if (__any(need_rescale)) {
        #pragma unroll
        for (int n = 0; n < 16; ++n)
          #pragma unroll
          for (int j = 0; j < 4; ++j) o[n][j] *= alpha[j];
      }

      // ---- P -> per-wave LDS (wave-private, no barrier) ----
      u16* Pw = Ps[w];
      #pragma unroll
      for (int ct = 0; ct < 4; ++ct)
        #pragma unroll
        for (int j = 0; j < 4; ++j) {
          int pr = kg*4 + j, pc = ct*16 + lr;
          int bo = (pr << 7) + (((pc << 1)) ^ ((pr & 7) << 4));
          *(u16*)((char*)Pw + bo) = f2bf(s[ct][j]);
        }

      // ---- O += P * V ----
      __builtin_amdgcn_s_setprio(1);
      #pragma unroll
      for (int kk = 0; kk < 2; ++kk) {
        int bo_p = (lr << 7) + ((((kk << 6) + (kg << 4))) ^ ((lr & 7) << 4));
        bf16x8 pa = *(const bf16x8*)((const char*)Pw + bo_p);
        #pragma unroll
        for (int n = 0; n < 16; ++n) {
          int dd = n*16 + lr;
          int bo = (dd << 7) + ((((kk << 6) + (kg << 4))) ^ ((dd & 7) << 4));
          bf16x8 vb = *(const bf16x8*)((const char*)Vs + bo);
          o[n] = __builtin_amdgcn_mfma_f32_16x16x32_bf16(pa, vb, o[n], 0, 0, 0);
        }
      }
      __builtin_amdgcn_s_setprio(0);
    }
  }

  // epilogue: normalize and store ctx[b][s][h*D+d] bf16
  #pragma unroll
  for (int j = 0; j < 4; ++j) lrun[j] = 1.f / lrun[j];
  int srow = q0 + wl*16 + kg*4;
  #pragma unroll
  for (int n = 0; n < 16; ++n)
    #pragma unroll
    for (int j = 0; j < 4; ++j) {
      float val = o[n][j] * lrun[j];
      int r = srow + j;
      int c = h*DD + n*16 + lr;
      ctx[(size_t)(b*SS + r) * EE + c] = f2bf(val);
    }
}

// ---------------- output projection + residual ----------------
__global__ __launch_bounds__(256) void proj_gemm_k(const u16* __restrict__ ctx,
                                                   const u16* __restrict__ wot,
                                                   const float* __restrict__ x,
                                                   float* __restrict__ y) {
  __shared__ u16 As[128*64], Bs[128*64];
  int bid = blockIdx.x;                 // 512 = 64 mt x 8 nt
  int mt = bid & 63, nt = bid >> 6;
  f32x4 acc[4][4];
  gemm128(ctx, EE, wot, EE, mt*128, nt*128, EE, As, Bs, acc);
  int t = threadIdx.x, lane = t & 63, w = t >> 6;
  int wr = w >> 1, wc = w & 1, lr = lane & 15, kg = lane >> 4;
  #pragma unroll
  for (int m = 0; m < 4; ++m)
    #pragma unroll
    for (int n = 0; n < 4; ++n)
      #pragma unroll
      for (int j = 0; j < 4; ++j) {
        int r = mt*128 + wr*64 + m*16 + kg*4 + j;
        int c = nt*128 + wc*64 + n*16 + lr;
        size_t idx = (size_t)r * EE + c;
        y[idx] = acc[m][n][j] + x[idx];
      }
}

// ---------------- LayerNorm in-place on y [8192][1024] ----------------
__global__ __launch_bounds__(256) void ln_k(float* __restrict__ y,
                                            const float* __restrict__ gamma,
                                            const float* __restrict__ beta) {
  int row = blockIdx.x;
  int t = threadIdx.x;
  float4 v = *((const float4*)(y + (size_t)row * EE) + t);
  float s = v.x + v.y + v.z + v.w;
  float ss = v.x*v.x + v.y*v.y + v.z*v.z + v.w*v.w;
  #pragma unroll
  for (int off = 1; off < 64; off <<= 1) {
    s  += __shfl_xor(s, off);
    ss += __shfl_xor(ss, off);
  }
  __shared__ float rs[4], rss[4];
  int w = t >> 6, lane = t & 63;
  if (lane == 0) { rs[w] = s; rss[w] = ss; }
  __syncthreads();
  s  = rs[0] + rs[1] + rs[2] + rs[3];
  ss = rss[0] + rss[1] + rss[2] + rss[3];
  float mean = s * (1.f / EE);
  float var  = ss * (1.f / EE) - mean * mean;
  float rstd = rsqrtf(var + 1e-6f);
  float4 g  = *((const float4*)gamma + t);
  float4 be = *((const float4*)beta + t);
  float4 ov;
  ov.x = (v.x - mean) * rstd * g.x + be.x;
  ov.y = (v.y - mean) * rstd * g.y + be.y;
  ov.z = (v.z - mean) * rstd * g.z + be.z;
  ov.w = (v.w - mean) * rstd * g.w + be.w;
  *((float4*)(y + (size_t)row * EE) + t) = ov;
}

extern "C" void kernel_launch(void* const* d_in, const int* in_sizes, int n_in,
                              void* d_out, int out_size, void* d_ws, size_t ws_size,
                              hipStream_t stream) {
  const float* x      = (const float*)d_in[0];
  const float* qkv_w  = (const float*)d_in[1];
  const float* out_w  = (const float*)d_in[2];
  const float* gamma  = (const float*)d_in[3];
  const float* beta   = (const float*)d_in[4];
  float* out = (float*)d_out;
  char* ws = (char*)d_ws;

  u16* xb  = (u16*)(ws);                       // 8192*1024 bf16 (16.78 MB)
  u16* ctx = xb;                               // reuse after QKV
  u16* wqt = (u16*)(ws + 16777216);            // [12][256][1024]
  u16* wot = (u16*)(ws + 23068672);            // [1024][1024]
  u16* Qb  = (u16*)(ws + 25165824);            // Q,K,V [B][H][S][D]
  u16* Kb  = Qb + (size_t)BB*HH*SS*DD;
  u16* Vb  = Kb + (size_t)BB*HH*SS*DD;

  cast_bf16_k<<<8192, 256, 0, stream>>>(x, xb, (BB*SS*EE)/4);
  transpose_cast_k<<<dim3(8, 32, 12), dim3(32, 8), 0, stream>>>(qkv_w, wqt, EE, DD);
  transpose_cast_k<<<dim3(32, 32, 1), dim3(32, 8), 0, stream>>>(out_w, wot, EE, EE);
  qkv_gemm_k<<<1536, 256, 0, stream>>>(xb, wqt, Qb);
  attn_k<<<256, 512, 0, stream>>>(Qb, Kb, Vb, ctx);
  proj_gemm_k<<<512, 256, 0, stream>>>(ctx, wot, x, out);
  ln_k<<<8192, 256, 0, stream>>>(out, gamma, beta);
}